// Round 5
// baseline (103.724 us; speedup 1.0000x reference)
//
#include <hip/hip_runtime.h>
#include <math.h>

#define FEAS 4096
#define K 64
#define BATCH 4096
#define NBLK 64

typedef float floatx4 __attribute__((ext_vector_type(4)));

// ws layout (floats):
//   ws[b*65 + j]  : column-j partial sum from block b   (j<64)
//   ws[b*65 + 64] : sum-of-squares partial from block b
//   ws[4160]      : FINAL scalar cross_sum (written by last-finishing block)
//   ws[4161]      : ticket counter (uint, zeroed by the 4-byte memset)
#define FINAL_IDX 4160
#define CTR_IDX   4161

__global__ __launch_bounds__(256) void cross_reduce_kernel(
    const float* __restrict__ cross, float* __restrict__ ws) {
    // 64 blocks x 256 threads; block b reduces rows [b*64, b*64+64) of V (4096x64)
    const int j  = threadIdx.x & 63;   // column 0..63
    const int rl = threadIdx.x >> 6;   // wave id 0..3
    const int row0 = blockIdx.x * 64;

    float s = 0.f, q = 0.f;
#pragma unroll
    for (int i = 0; i < 16; ++i) {
        const float v = cross[(size_t)(row0 + rl * 16 + i) * K + j];
        s += v;
        q += v * v;
    }

    __shared__ float ls[256];
    __shared__ float lq[256];
    ls[threadIdx.x] = s;
    lq[threadIdx.x] = q;
    __syncthreads();

    __shared__ bool amLast;
    if (threadIdx.x < 64) {
        const float cs = ls[j] + ls[j + 64] + ls[j + 128] + ls[j + 192];
        ws[blockIdx.x * 65 + j] = cs;

        float cq = lq[j] + lq[j + 64] + lq[j + 128] + lq[j + 192];
#pragma unroll
        for (int off = 32; off; off >>= 1) cq += __shfl_down(cq, off, 64);
        if (j == 0) {
            ws[blockIdx.x * 65 + 64] = cq;
            __threadfence();  // release our partials (device scope)
            unsigned old = atomicAdd((unsigned*)&ws[CTR_IDX], 1u);
            amLast = (old == NBLK - 1);
        }
    }
    __syncthreads();

    // Last-finishing block folds all 64 partials into the final scalar.
    if (amLast && threadIdx.x < 64) {
        __threadfence();  // acquire all other blocks' partials
        float csum = 0.f;
#pragma unroll 8
        for (int b = 0; b < NBLK; ++b) csum += ws[b * 65 + threadIdx.x];
        float val = csum * csum + ws[threadIdx.x * 65 + 64];
#pragma unroll
        for (int off = 32; off; off >>= 1) val += __shfl_down(val, off, 64);
        if (threadIdx.x == 0) ws[FINAL_IDX] = 0.5f * val;
    }
}

// Wave-per-row GEMV: 1024 blocks x 256 threads; wave w owns row 4*blk+w.
// No LDS, no __syncthreads — pure shuffle reduce per wave.
__global__ __launch_bounds__(256) void gemv_sigmoid_kernel(
    const float* __restrict__ x, const float* __restrict__ w,
    const float* __restrict__ bias, const float* __restrict__ ws,
    float* __restrict__ out) {
    const int wave = threadIdx.x >> 6;
    const int lane = threadIdx.x & 63;
    const int row  = blockIdx.x * 4 + wave;

    const float cross_sum = ws[FINAL_IDX];
    const float b0 = bias[0];

    const floatx4* __restrict__ xr = (const floatx4*)(x + (size_t)row * FEAS);
    const floatx4* __restrict__ wv = (const floatx4*)w;

    float acc = 0.f;
#pragma unroll
    for (int i = 0; i < 16; ++i) {
        const int idx = lane + i * 64;       // 64 lanes x 16B = 1KB/instr, coalesced
        const floatx4 a = xr[idx];
        const floatx4 b = wv[idx];           // L1-resident (16KB, reused chip-wide)
        acc += a.x * b.x + a.y * b.y + a.z * b.z + a.w * b.w;
    }

#pragma unroll
    for (int off = 32; off; off >>= 1) acc += __shfl_down(acc, off, 64);

    if (lane == 0) {
        const float y = acc + b0 + cross_sum;
        out[row] = 1.0f / (1.0f + expf(-y));
    }
}

extern "C" void kernel_launch(void* const* d_in, const int* in_sizes, int n_in,
                              void* d_out, int out_size, void* d_ws, size_t ws_size,
                              hipStream_t stream) {
    const float* x     = (const float*)d_in[0];  // (4096, 4096)
    const float* cross = (const float*)d_in[1];  // (4096, 1, 64)
    const float* w     = (const float*)d_in[2];  // (1, 4096)
    const float* b     = (const float*)d_in[3];  // (1,)
    float* out = (float*)d_out;                  // (4096, 1)
    float* ws  = (float*)d_ws;

    // Zero only the 4-byte ticket counter (ws is re-poisoned to 0xAA each run).
    hipMemsetAsync(ws + CTR_IDX, 0, sizeof(unsigned), stream);

    cross_reduce_kernel<<<NBLK, 256, 0, stream>>>(cross, ws);
    gemv_sigmoid_kernel<<<BATCH / 4, 256, 0, stream>>>(x, w, b, ws, out);
}